// Round 1
// baseline (430.691 us; speedup 1.0000x reference)
//
#include <hip/hip_runtime.h>

#define N_TOK 8
#define C_CH 64
#define HEADS 8
#define EPS 1e-5f

// LDS column stride for q/k/v: 9 floats (8 tokens + 1 pad) -> conflict-free
// phase-1 writes (9*t mod 32 covers all banks since gcd(9,32)=1).
#define QS 9

__global__ __launch_bounds__(512) void fused_chan_attn(
    const float* __restrict__ emb,
    const float* __restrict__ Wq,
    const float* __restrict__ Wk,
    const float* __restrict__ Wv,
    const float* __restrict__ Wo,
    float* __restrict__ out)
{
    __shared__ float emb_s[N_TOK * C_CH];     // 512 f
    __shared__ float q_s[512 * QS];           // 4608 f
    __shared__ float k_s[512 * QS];
    __shared__ float v_s[512 * QS];
    __shared__ float ctx_s[N_TOK * 512];      // 4096 f  (ctx[n][ci*8+h])

    const int bp = blockIdx.x;     // 0..3455
    const int t  = threadIdx.x;    // 0..511

    // ---- phase 0: stage emb tile (8 tokens x 64 ch) ----
    emb_s[t] = emb[bp * (N_TOK * C_CH) + t];
    __syncthreads();

    // ---- phase 1: QKV projection; thread t owns output column t ----
    {
        float aq[N_TOK], ak[N_TOK], av[N_TOK];
        #pragma unroll
        for (int n = 0; n < N_TOK; ++n) { aq[n] = 0.f; ak[n] = 0.f; av[n] = 0.f; }
        #pragma unroll 8
        for (int j = 0; j < C_CH; ++j) {
            const float wq = Wq[j * 512 + t];
            const float wk = Wk[j * 512 + t];
            const float wv = Wv[j * 512 + t];
            #pragma unroll
            for (int n = 0; n < N_TOK; ++n) {
                const float e = emb_s[n * C_CH + j];
                aq[n] += e * wq;
                ak[n] += e * wk;
                av[n] += e * wv;
            }
        }
        #pragma unroll
        for (int n = 0; n < N_TOK; ++n) {
            q_s[t * QS + n] = aq[n];
            k_s[t * QS + n] = ak[n];
            v_s[t * QS + n] = av[n];
        }
    }
    __syncthreads();

    // ---- phase 2: per-head channel attention; wave = head, lane = row ci ----
    const int h  = t >> 6;   // wave id == head
    const int ci = t & 63;   // lane == attention row (channel)

    // q row for this (ci, h): q_full[n, ci*8+h]
    float qrow[N_TOK];
    #pragma unroll
    for (int n = 0; n < N_TOK; ++n) qrow[n] = q_s[(ci * HEADS + h) * QS + n];

    // attn row: attn[ci][d] = sum_n q[n,ci]_h * k[n,d]_h
    float arow[C_CH];
    #pragma unroll
    for (int d = 0; d < C_CH; ++d) {
        float s = 0.f;
        #pragma unroll
        for (int n = 0; n < N_TOK; ++n)
            s += qrow[n] * k_s[(d * HEADS + h) * QS + n];   // broadcast read
        arow[d] = s;
    }

    // instance norm over the whole 64x64 map (per bp,h): cross-lane reduce
    float sum = 0.f, ssq = 0.f;
    #pragma unroll
    for (int d = 0; d < C_CH; ++d) { sum += arow[d]; ssq += arow[d] * arow[d]; }
    #pragma unroll
    for (int m = 1; m < 64; m <<= 1) {
        sum += __shfl_xor(sum, m);
        ssq += __shfl_xor(ssq, m);
    }
    const float mean = sum * (1.0f / 4096.0f);
    const float var  = ssq * (1.0f / 4096.0f) - mean * mean;
    const float rstd = rsqrtf(var + EPS);

    // normalize + row softmax (row is lane-local)
    float mx = -3.0e38f;
    #pragma unroll
    for (int d = 0; d < C_CH; ++d) {
        arow[d] = (arow[d] - mean) * rstd;
        mx = fmaxf(mx, arow[d]);
    }
    float es = 0.f;
    #pragma unroll
    for (int d = 0; d < C_CH; ++d) {
        arow[d] = expf(arow[d] - mx);
        es += arow[d];
    }
    const float inv = 1.0f / es;

    // ctx[ci][n] = sum_d attn[ci][d] * v[n, d*8+h]
    float ctx[N_TOK];
    #pragma unroll
    for (int n = 0; n < N_TOK; ++n) ctx[n] = 0.f;
    #pragma unroll
    for (int d = 0; d < C_CH; ++d) {
        const float a = arow[d] * inv;
        #pragma unroll
        for (int n = 0; n < N_TOK; ++n)
            ctx[n] += a * v_s[(d * HEADS + h) * QS + n];    // broadcast read
    }

    // stage ctx in (c heads) order: ctx_s[n][ci*8+h]
    #pragma unroll
    for (int n = 0; n < N_TOK; ++n)
        ctx_s[n * 512 + ci * HEADS + h] = ctx[n];
    __syncthreads();

    // ---- phase 3: output projection + token rearrange ----
    // wave n_o handles token-local index n_o; lane co = output channel
    const int n_o = t >> 6;
    const int co  = t & 63;
    float acc = 0.f;
    #pragma unroll 8
    for (int k = 0; k < 512; ++k)
        acc += ctx_s[n_o * 512 + k] * Wo[k * C_CH + co];

    // rearrange '(b d h w) heads c (p1 p2 p3) -> b (d p1 h p2 w p3) (c heads)'
    const int b  = bp / 27;
    const int r  = bp % 27;
    const int dd = r / 9;
    const int hh = (r / 3) % 3;
    const int ww = r % 3;
    const int p1 = (n_o >> 2) & 1;
    const int p2 = (n_o >> 1) & 1;
    const int p3 = n_o & 1;
    const int token = ((((dd * 2 + p1) * 3 + hh) * 2 + p2) * 3 + ww) * 2 + p3;

    out[(b * 216 + token) * C_CH + co] = acc;
}

extern "C" void kernel_launch(void* const* d_in, const int* in_sizes, int n_in,
                              void* d_out, int out_size, void* d_ws, size_t ws_size,
                              hipStream_t stream) {
    const float* emb = (const float*)d_in[0];
    const float* Wq  = (const float*)d_in[1];
    const float* Wk  = (const float*)d_in[2];
    const float* Wv  = (const float*)d_in[3];
    const float* Wo  = (const float*)d_in[4];
    float* out = (float*)d_out;

    const int Bp = in_sizes[0] / (N_TOK * C_CH);   // 3456
    fused_chan_attn<<<Bp, 512, 0, stream>>>(emb, Wq, Wk, Wv, Wo, out);
}

// Round 2
// 271.792 us; speedup vs baseline: 1.5846x; 1.5846x over previous
//
#include <hip/hip_runtime.h>

#define N_TOK 8
#define C_CH 64
#define HEADS 8
#define EPS 1e-5f

// Thread mapping (all phases, 512 threads):
//   P1: thread t computes QKV output column t (q kept in registers).
//   P2: h = t&7, ci = t>>3  ->  q column needed is ci*HEADS+h == t (identity!)
//   P3: n_o = t>>6, co-group g = t&15, k-slice s = (t>>4)&3 (split-K by 4)
__global__ __launch_bounds__(512) void fused_chan_attn(
    const float* __restrict__ emb,
    const float* __restrict__ Wq,
    const float* __restrict__ Wk,
    const float* __restrict__ Wv,
    const float* __restrict__ Wo,
    float* __restrict__ out)
{
    __shared__ float emb_s[N_TOK * C_CH];      // 512 f
    __shared__ float part_sum[64];             // [wave][h]
    __shared__ float part_ssq[64];
    __shared__ float kv_s[2 * 512 * N_TOK];    // k | v ; k region reused as ctx

    float* __restrict__ k_s   = kv_s;              // [512][8], 32B rows
    float* __restrict__ v_s   = kv_s + 512 * 8;    // [512][8]
    float* __restrict__ ctx_s = kv_s;              // overlay after PV done

    const int bp = blockIdx.x;     // 0..3455
    const int t  = threadIdx.x;    // 0..511

    // ---- P0: stage emb (8 tokens x 64 ch) ----
    emb_s[t] = emb[bp * 512 + t];
    __syncthreads();

    // ---- P1: QKV projection, thread t = output column t ----
    float q[N_TOK];
    {
        float ak[N_TOK], av[N_TOK];
        #pragma unroll
        for (int n = 0; n < N_TOK; ++n) { q[n] = 0.f; ak[n] = 0.f; av[n] = 0.f; }

        #pragma unroll 4
        for (int j4 = 0; j4 < C_CH / 4; ++j4) {
            float4 e4[N_TOK];
            #pragma unroll
            for (int n = 0; n < N_TOK; ++n)
                e4[n] = *(const float4*)&emb_s[n * C_CH + j4 * 4];
            #pragma unroll
            for (int jj = 0; jj < 4; ++jj) {
                const int j = j4 * 4 + jj;
                const float wq = Wq[j * 512 + t];
                const float wk = Wk[j * 512 + t];
                const float wv = Wv[j * 512 + t];
                #pragma unroll
                for (int n = 0; n < N_TOK; ++n) {
                    const float e = (jj == 0) ? e4[n].x : (jj == 1) ? e4[n].y
                                  : (jj == 2) ? e4[n].z : e4[n].w;
                    q[n]  += e * wq;
                    ak[n] += e * wk;
                    av[n] += e * wv;
                }
            }
        }
        float4* kd = (float4*)&k_s[t * 8];
        float4* vd = (float4*)&v_s[t * 8];
        kd[0] = make_float4(ak[0], ak[1], ak[2], ak[3]);
        kd[1] = make_float4(ak[4], ak[5], ak[6], ak[7]);
        vd[0] = make_float4(av[0], av[1], av[2], av[3]);
        vd[1] = make_float4(av[4], av[5], av[6], av[7]);
    }
    __syncthreads();

    // ---- P2: channel attention; lane owns attn row ci of head h ----
    const int h  = t & 7;
    const int ci = t >> 3;
    (void)ci;

    float arow[C_CH];
    float sum = 0.f, ssq = 0.f;
    #pragma unroll
    for (int d = 0; d < C_CH; ++d) {
        const float4* kr = (const float4*)&k_s[(d * HEADS + h) * 8];
        const float4 k0 = kr[0], k1 = kr[1];
        const float s = q[0]*k0.x + q[1]*k0.y + q[2]*k0.z + q[3]*k0.w
                      + q[4]*k1.x + q[5]*k1.y + q[6]*k1.z + q[7]*k1.w;
        arow[d] = s;
        sum += s;
        ssq += s * s;
    }

    // instance-norm reduce over all 64 rows of (bp,h): 8 lanes/wave share h,
    // xor-reduce within wave, then combine the 8 waves via LDS.
    #pragma unroll
    for (int m = 8; m < 64; m <<= 1) {
        sum += __shfl_xor(sum, m);
        ssq += __shfl_xor(ssq, m);
    }
    const int wv_id = t >> 6;
    if ((t & 63) < 8) {            // lane l<8 has h==l
        part_sum[wv_id * 8 + h] = sum;
        part_ssq[wv_id * 8 + h] = ssq;
    }
    __syncthreads();
    sum = 0.f; ssq = 0.f;
    #pragma unroll
    for (int w2 = 0; w2 < 8; ++w2) {
        sum += part_sum[w2 * 8 + h];
        ssq += part_ssq[w2 * 8 + h];
    }

    const float mean = sum * (1.0f / 4096.0f);
    const float var  = ssq * (1.0f / 4096.0f) - mean * mean;
    const float rstd = rsqrtf(var + EPS);

    // normalize + row softmax (row is lane-local)
    float mx = -3.0e38f;
    #pragma unroll
    for (int d = 0; d < C_CH; ++d) {
        arow[d] = (arow[d] - mean) * rstd;
        mx = fmaxf(mx, arow[d]);
    }
    float es = 0.f;
    #pragma unroll
    for (int d = 0; d < C_CH; ++d) {
        arow[d] = __expf(arow[d] - mx);
        es += arow[d];
    }
    const float inv = 1.0f / es;

    // ctx[ci][n] = sum_d attn[ci][d] * v[n, d*8+h]
    float c[N_TOK];
    #pragma unroll
    for (int n = 0; n < N_TOK; ++n) c[n] = 0.f;
    #pragma unroll
    for (int d = 0; d < C_CH; ++d) {
        const float4* vr = (const float4*)&v_s[(d * HEADS + h) * 8];
        const float4 v0 = vr[0], v1 = vr[1];
        const float a = arow[d] * inv;
        c[0] += a * v0.x; c[1] += a * v0.y; c[2] += a * v0.z; c[3] += a * v0.w;
        c[4] += a * v1.x; c[5] += a * v1.y; c[6] += a * v1.z; c[7] += a * v1.w;
    }
    __syncthreads();   // all k_s/v_s reads done before ctx overlay

    // ctx column index = ci*HEADS+h == t  -> coalesced, conflict-free
    #pragma unroll
    for (int n = 0; n < N_TOK; ++n)
        ctx_s[n * 512 + t] = c[n];
    __syncthreads();

    // ---- P3: output projection (split-K by 4) + token rearrange ----
    const int n_o = t >> 6;
    const int g   = t & 15;          // 4-channel output group
    const int s   = (t >> 4) & 3;    // k-slice of 128

    const float4* Wo4 = (const float4*)Wo;                        // [512][16]
    const float4* cx4 = (const float4*)&ctx_s[n_o * 512 + s * 128];
    float4 acc = make_float4(0.f, 0.f, 0.f, 0.f);
    #pragma unroll 8
    for (int kk = 0; kk < 128; kk += 4) {
        const float4 cc = cx4[kk >> 2];
        const int kb = (s * 128 + kk) * 16 + g;
        const float4 w0 = Wo4[kb];
        const float4 w1 = Wo4[kb + 16];
        const float4 w2 = Wo4[kb + 32];
        const float4 w3 = Wo4[kb + 48];
        acc.x += cc.x*w0.x + cc.y*w1.x + cc.z*w2.x + cc.w*w3.x;
        acc.y += cc.x*w0.y + cc.y*w1.y + cc.z*w2.y + cc.w*w3.y;
        acc.z += cc.x*w0.z + cc.y*w1.z + cc.z*w2.z + cc.w*w3.z;
        acc.w += cc.x*w0.w + cc.y*w1.w + cc.z*w2.w + cc.w*w3.w;
    }
    acc.x += __shfl_xor(acc.x, 16); acc.x += __shfl_xor(acc.x, 32);
    acc.y += __shfl_xor(acc.y, 16); acc.y += __shfl_xor(acc.y, 32);
    acc.z += __shfl_xor(acc.z, 16); acc.z += __shfl_xor(acc.z, 32);
    acc.w += __shfl_xor(acc.w, 16); acc.w += __shfl_xor(acc.w, 32);

    if (s == 0) {
        const int b  = bp / 27;
        const int r  = bp % 27;
        const int dd = r / 9;
        const int hh = (r / 3) % 3;
        const int ww = r % 3;
        const int p1 = (n_o >> 2) & 1;
        const int p2 = (n_o >> 1) & 1;
        const int p3 = n_o & 1;
        const int token = ((((dd * 2 + p1) * 3 + hh) * 2 + p2) * 3 + ww) * 2 + p3;
        *(float4*)&out[(b * 216 + token) * C_CH + g * 4] = acc;
    }
}

extern "C" void kernel_launch(void* const* d_in, const int* in_sizes, int n_in,
                              void* d_out, int out_size, void* d_ws, size_t ws_size,
                              hipStream_t stream) {
    const float* emb = (const float*)d_in[0];
    const float* Wq  = (const float*)d_in[1];
    const float* Wk  = (const float*)d_in[2];
    const float* Wv  = (const float*)d_in[3];
    const float* Wo  = (const float*)d_in[4];
    float* out = (float*)d_out;

    const int Bp = in_sizes[0] / (N_TOK * C_CH);   // 3456
    fused_chan_attn<<<Bp, 512, 0, stream>>>(emb, Wq, Wk, Wv, Wo, out);
}

// Round 3
// 140.266 us; speedup vs baseline: 3.0705x; 1.9377x over previous
//
#include <hip/hip_runtime.h>
#include <stdint.h>

#define N_TOK 8
#define C_CH 64
#define HEADS 8

typedef unsigned short u16;
typedef unsigned int   u32;
typedef short short8 __attribute__((ext_vector_type(8)));
typedef float f32x4  __attribute__((ext_vector_type(4)));

#define MFMA(a, b, c) __builtin_amdgcn_mfma_f32_16x16x32_bf16((a), (b), (c), 0, 0, 0)

__device__ __forceinline__ u16 bf_trunc(float x) {
    return (u16)(__builtin_bit_cast(u32, x) >> 16);
}
__device__ __forceinline__ float bf_to_f(u16 h) {
    u32 b = ((u32)h) << 16; return __builtin_bit_cast(float, b);
}
__device__ __forceinline__ u16 bf_rne(float x) {
    u32 b = __builtin_bit_cast(u32, x);
    return (u16)((b + 0x7FFF + ((b >> 16) & 1)) >> 16);
}

// ---------------------------------------------------------------------------
// prep kernel: convert weights to MFMA-B-fragment-ordered bf16 hi/lo in ws.
// ws layout (u16): frags 0..191 = {Wq,Wk,Wv}, frags 192..255 = Wo.
// frag3 = mat*64 + kt*32 + nt ; wo frag = kt*4 + nt.
// element (frag, sel, lane, j) at frag*1024 + sel*512 + lane*8 + j.
// B[k][col], k = kt*32 + (lane>>4)*8 + j, col = nt*16 + (lane&15).
// ---------------------------------------------------------------------------
__global__ __launch_bounds__(512) void prep_weights(
    const float* __restrict__ Wq, const float* __restrict__ Wk,
    const float* __restrict__ Wv, const float* __restrict__ Wo,
    u16* __restrict__ ws)
{
    int idx = blockIdx.x * 512 + threadIdx.x;     // 0..262143
    int frag = idx >> 10;
    int rem  = idx & 1023;
    int sel  = rem >> 9;
    int l    = (rem >> 3) & 63;
    int j    = rem & 7;
    float v;
    if (frag < 192) {
        int mat = frag >> 6;
        int kt  = (frag >> 5) & 1;
        int nt  = frag & 31;
        int k   = kt * 32 + (l >> 4) * 8 + j;
        int col = nt * 16 + (l & 15);
        const float* W = (mat == 0) ? Wq : ((mat == 1) ? Wk : Wv);
        v = W[k * 512 + col];
    } else {
        int f   = frag - 192;
        int kt  = f >> 2;
        int nt  = f & 3;
        int k   = kt * 32 + (l >> 4) * 8 + j;
        int col = nt * 16 + (l & 15);
        v = Wo[k * 64 + col];
    }
    u16 hi = bf_trunc(v);
    u16 o  = hi;
    if (sel) o = bf_trunc(v - bf_to_f(hi));
    ws[idx] = o;
}

// ---------------------------------------------------------------------------
// main fused kernel: 2 patches per block, 512 threads (8 waves).
// ---------------------------------------------------------------------------
__global__ __launch_bounds__(512, 2) void fused_attn_mfma(
    const float* __restrict__ emb,
    const u16*  __restrict__ w3,     // 192 frags (qkv)
    const u16*  __restrict__ wo,     // 64 frags
    float* __restrict__ out)
{
    // arena (u16 units):
    //   q_pk  [16ph][64c][16]  @ 0       (8192 u16 region 0..16383)
    //   k_pk                    @ 16384
    //   v_b   [16ph][8n][64d]  @ 32768   (8192)
    //   a_emb [2sel][2kt][64][8] @ 40960 (2048)
    //   zero  16 u16            @ 43008
    // overlays:
    //   a_lds per wave: chunk0 = q_pk + w*2048, chunk1 = k_pk + w*2048
    //   ctxA_hi [16][520] @ 0, ctxA_lo @ 8320  (total 16640 u16 < 32768)
    //   partials (f32, 4KB) @ u16 offset 32768
    __shared__ u16 arena[43024];
    u16* q_pk  = arena;
    u16* k_pk  = arena + 16384;
    u16* v_b   = arena + 32768;
    u16* a_emb = arena + 40960;
    u16* zerob = arena + 43008;

    const int t   = threadIdx.x;
    const int l   = t & 63;
    const int w   = t >> 6;
    const int g   = l >> 4;
    const int l15 = l & 15;

    // ---- P0: emb -> A fragments (bf16 hi/lo), zero buf ----
    {
        if (t < 8) ((u32*)zerob)[t] = 0u;
        int e   = t * 2;
        int row = e >> 6;          // 0..15 = p*8 + n
        int j   = e & 63;
        float2 x2 = *(const float2*)&emb[(size_t)blockIdx.x * 1024 + e];
        int kt = j >> 5, gg = (j >> 3) & 3, jj = j & 7;
        int lane = row + gg * 16;
        u16 h0 = bf_trunc(x2.x), h1 = bf_trunc(x2.y);
        u16 q0 = bf_trunc(x2.x - bf_to_f(h0)), q1 = bf_trunc(x2.y - bf_to_f(h1));
        *(u32*)&a_emb[((0 * 2 + kt) * 64 + lane) * 8 + jj] = (u32)h0 | ((u32)h1 << 16);
        *(u32*)&a_emb[((1 * 2 + kt) * 64 + lane) * 8 + jj] = (u32)q0 | ((u32)q1 << 16);
    }
    __syncthreads();

    // ---- P1: QKV = emb @ {Wq,Wk,Wv}, bf16x3, 12 tiles per wave ----
    {
        short8 aeh[2], ael[2];
        #pragma unroll
        for (int kt = 0; kt < 2; ++kt) {
            aeh[kt] = *(const short8*)&a_emb[(0 * 2 + kt) * 512 + l * 8];
            ael[kt] = *(const short8*)&a_emb[(1 * 2 + kt) * 512 + l * 8];
        }
        #pragma unroll
        for (int i = 0; i < 12; ++i) {
            int tid = w * 12 + i;            // 0..95
            int mat = tid >> 5;
            int nt  = tid & 31;
            f32x4 acc = {0.f, 0.f, 0.f, 0.f};
            #pragma unroll
            for (int kt = 0; kt < 2; ++kt) {
                const u16* bb = &w3[(mat * 64 + kt * 32 + nt) * 1024];
                short8 bh = *(const short8*)&bb[l * 8];
                short8 bl = *(const short8*)&bb[512 + l * 8];
                acc = MFMA(aeh[kt], bh, acc);
                acc = MFMA(ael[kt], bh, acc);
                acc = MFMA(aeh[kt], bl, acc);
            }
            // C/D: col = nt*16 + l15, rows = g*4 + r (= p*8 + n)
            int col = nt * 16 + l15;
            int c = col >> 3, hh = col & 7;
            int p = g >> 1, n0 = (g & 1) * 4;
            int ph = p * 8 + hh;
            if (mat < 2) {
                u16* dst = ((mat == 0) ? q_pk : k_pk) + (ph * 64 + c) * 16 + n0;
                u16 h0 = bf_trunc(acc[0]), h1 = bf_trunc(acc[1]);
                u16 h2 = bf_trunc(acc[2]), h3 = bf_trunc(acc[3]);
                *(u32*)&dst[0] = (u32)h0 | ((u32)h1 << 16);
                *(u32*)&dst[2] = (u32)h2 | ((u32)h3 << 16);
                u16 q0 = bf_trunc(acc[0] - bf_to_f(h0)), q1 = bf_trunc(acc[1] - bf_to_f(h1));
                u16 q2 = bf_trunc(acc[2] - bf_to_f(h2)), q3 = bf_trunc(acc[3] - bf_to_f(h3));
                *(u32*)&dst[8]  = (u32)q0 | ((u32)q1 << 16);
                *(u32*)&dst[10] = (u32)q2 | ((u32)q3 << 16);
            } else {
                #pragma unroll
                for (int r = 0; r < 4; ++r) {
                    int n = n0 + r;
                    v_b[(ph * 8 + n) * 64 + (c ^ ((n & 3) << 4))] = bf_rne(acc[r]);
                }
            }
        }
    }
    __syncthreads();

    // ---- P2: per-(patch,head) channel attention. wave owns ph0, ph0+1 ----
    const int ph0 = w * 2;
    f32x4 att[2][4][4];

    #pragma unroll
    for (int pp = 0; pp < 2; ++pp) {
        int ph = ph0 + pp;
        short8 qa[4], kb[4];
        #pragma unroll
        for (int mt = 0; mt < 4; ++mt) {
            int c = mt * 16 + l15;
            const u16* ap = (g == 3) ? zerob : &q_pk[(ph * 64 + c) * 16 + (g & 1) * 8];
            qa[mt] = *(const short8*)ap;
        }
        #pragma unroll
        for (int nt = 0; nt < 4; ++nt) {
            int d = nt * 16 + l15;
            const u16* bp_ = (g == 3) ? zerob : &k_pk[(ph * 64 + d) * 16 + ((g == 2) ? 8 : 0)];
            kb[nt] = *(const short8*)bp_;
        }
        #pragma unroll
        for (int mt = 0; mt < 4; ++mt)
            #pragma unroll
            for (int nt = 0; nt < 4; ++nt) {
                f32x4 z = {0.f, 0.f, 0.f, 0.f};
                att[pp][mt][nt] = MFMA(qa[mt], kb[nt], z);
            }
    }

    // softmax(instance_norm(att)) + PV, per map
    u16* chunk0 = q_pk + w * 2048;     // wave-private a_lds (32 rows x 64)
    u16* chunk1 = k_pk + w * 2048;
    f32x4 ctx_acc[2][4];

    #pragma unroll
    for (int pp = 0; pp < 2; ++pp) {
        int ph = ph0 + pp;
        // map stats (whole 64x64 map lives in this wave)
        float sum = 0.f, ssq = 0.f;
        #pragma unroll
        for (int mt = 0; mt < 4; ++mt)
            #pragma unroll
            for (int nt = 0; nt < 4; ++nt)
                #pragma unroll
                for (int r = 0; r < 4; ++r) {
                    float x = att[pp][mt][nt][r];
                    sum += x; ssq += x * x;
                }
        #pragma unroll
        for (int m = 1; m < 64; m <<= 1) {
            sum += __shfl_xor(sum, m);
            ssq += __shfl_xor(ssq, m);
        }
        float mu  = sum * (1.f / 4096.f);
        float var = ssq * (1.f / 4096.f) - mu * mu;
        // softmax is shift-invariant: mean cancels; only rstd matters.
        float rs2 = rsqrtf(var + 1e-5f) * 1.44269504f;   // rstd * log2(e)

        float rinv[4][4];
        #pragma unroll
        for (int mt = 0; mt < 4; ++mt)
            #pragma unroll
            for (int r = 0; r < 4; ++r) {
                float mx = fmaxf(fmaxf(att[pp][mt][0][r], att[pp][mt][1][r]),
                                 fmaxf(att[pp][mt][2][r], att[pp][mt][3][r]));
                #pragma unroll
                for (int m = 1; m < 16; m <<= 1) mx = fmaxf(mx, __shfl_xor(mx, m));
                float rm2 = mx * rs2;
                float s = 0.f;
                #pragma unroll
                for (int nt = 0; nt < 4; ++nt) {
                    float p_ = __builtin_amdgcn_exp2f(att[pp][mt][nt][r] * rs2 - rm2);
                    att[pp][mt][nt][r] = p_;
                    s += p_;
                }
                #pragma unroll
                for (int m = 1; m < 16; m <<= 1) s += __shfl_xor(s, m);
                rinv[mt][r] = __builtin_amdgcn_rcpf(s);
            }

        // write attn (bf16, normalized) to wave-private a_lds, XOR-swizzled
        #pragma unroll
        for (int mt = 0; mt < 4; ++mt) {
            u16* base = (mt < 2) ? chunk0 : chunk1;
            #pragma unroll
            for (int nt = 0; nt < 4; ++nt)
                #pragma unroll
                for (int r = 0; r < 4; ++r) {
                    int c = mt * 16 + g * 4 + r;
                    int d = nt * 16 + l15;
                    base[(c & 31) * 64 + (d ^ (g << 4))] =
                        bf_rne(att[pp][mt][nt][r] * rinv[mt][r]);
                }
        }

        // PV: ctx[c][n] = sum_d attn[c][d] * v[d][n]
        int gw = l15 >> 2;
        #pragma unroll
        for (int mt = 0; mt < 4; ++mt) ctx_acc[pp][mt] = (f32x4){0.f, 0.f, 0.f, 0.f};
        #pragma unroll
        for (int kt = 0; kt < 2; ++kt) {
            int n = l & 7;
            short8 vb = *(const short8*)&v_b[(ph * 8 + n) * 64 +
                                             ((kt * 32 + g * 8) ^ ((n & 3) << 4))];
            #pragma unroll
            for (int mt = 0; mt < 4; ++mt) {
                u16* base = (mt < 2) ? chunk0 : chunk1;
                int c = mt * 16 + l15;
                short8 aa = *(const short8*)&base[(c & 31) * 64 +
                                                  ((kt * 32 + g * 8) ^ (gw << 4))];
                ctx_acc[pp][mt] = MFMA(aa, vb, ctx_acc[pp][mt]);
            }
        }
    }
    __syncthreads();    // all QK/PV LDS regions now dead

    // ---- ctx -> ctxA (bf16 hi/lo, A-fragment-friendly, swizzled) ----
    u16* ctxA_hi = arena;            // [16 pn][520]
    u16* ctxA_lo = arena + 8320;
    if (l15 < 8) {
        #pragma unroll
        for (int pp = 0; pp < 2; ++pp) {
            int ph = ph0 + pp;
            int p = ph >> 3, hh = ph & 7;
            int pn = p * 8 + l15;
            #pragma unroll
            for (int mt = 0; mt < 4; ++mt)
                #pragma unroll
                for (int r = 0; r < 4; ++r) {
                    int c = mt * 16 + g * 4 + r;
                    int k = (c * 8 + hh) ^ ((pn & 3) << 4);
                    float v = ctx_acc[pp][mt][r];
                    u16 hi = bf_trunc(v);
                    ctxA_hi[pn * 520 + k] = hi;
                    ctxA_lo[pn * 520 + k] = bf_trunc(v - bf_to_f(hi));
                }
        }
    }
    __syncthreads();

    // ---- P3: out = ctx @ Wo (bf16x3, split-K over wave pairs) ----
    {
        int nt = w & 3;
        int kb = (w >> 2) * 8;
        f32x4 oacc = {0.f, 0.f, 0.f, 0.f};
        #pragma unroll
        for (int ki = 0; ki < 8; ++ki) {
            int kt = kb + ki;
            int kk = (kt * 32 + g * 8) ^ ((l15 & 3) << 4);
            short8 ah = *(const short8*)&ctxA_hi[l15 * 520 + kk];
            short8 al = *(const short8*)&ctxA_lo[l15 * 520 + kk];
            const u16* bb = &wo[(kt * 4 + nt) * 1024];
            short8 bh = *(const short8*)&bb[l * 8];
            short8 bl = *(const short8*)&bb[512 + l * 8];
            oacc = MFMA(ah, bh, oacc);
            oacc = MFMA(al, bh, oacc);
            oacc = MFMA(ah, bl, oacc);
        }
        float* part = (float*)&arena[32768];    // 4KB scratch (over v_b)
        if (w >= 4) {
            *(f32x4*)&part[((w - 4) * 64 + l) * 4] = oacc;
        }
        __syncthreads();
        if (w < 4) {
            f32x4 o2 = *(const f32x4*)&part[(w * 64 + l) * 4];
            oacc += o2;
            int col = nt * 16 + l15;
            #pragma unroll
            for (int r = 0; r < 4; ++r) {
                int pn = g * 4 + r;
                int p = pn >> 3, n = pn & 7;
                int bp = blockIdx.x * 2 + p;
                int b = bp / 27, rr = bp % 27;
                int dd = rr / 9, hh2 = (rr / 3) % 3, ww2 = rr % 3;
                int token = ((((dd * 2 + (n >> 2)) * 3 + hh2) * 2 + ((n >> 1) & 1)) * 3
                             + ww2) * 2 + (n & 1);
                out[((size_t)b * 216 + token) * 64 + col] = oacc[r];
            }
        }
    }
}

// ---------------------------------------------------------------------------
// fallback (round-2 kernel) if ws is too small for weight preconversion
// ---------------------------------------------------------------------------
__global__ __launch_bounds__(512) void fused_fallback(
    const float* __restrict__ emb, const float* __restrict__ Wq,
    const float* __restrict__ Wk,  const float* __restrict__ Wv,
    const float* __restrict__ Wo,  float* __restrict__ out)
{
    __shared__ float emb_s[N_TOK * C_CH];
    __shared__ float part_sum[64];
    __shared__ float part_ssq[64];
    __shared__ float kv_s[2 * 512 * N_TOK];
    float* k_s = kv_s;
    float* v_s = kv_s + 512 * 8;
    float* ctx_s = kv_s;
    const int bp = blockIdx.x;
    const int t  = threadIdx.x;
    emb_s[t] = emb[bp * 512 + t];
    __syncthreads();
    float q[N_TOK];
    {
        float ak[N_TOK], av[N_TOK];
        #pragma unroll
        for (int n = 0; n < N_TOK; ++n) { q[n] = 0.f; ak[n] = 0.f; av[n] = 0.f; }
        #pragma unroll 8
        for (int j = 0; j < C_CH; ++j) {
            const float wq = Wq[j * 512 + t], wk = Wk[j * 512 + t], wv = Wv[j * 512 + t];
            #pragma unroll
            for (int n = 0; n < N_TOK; ++n) {
                const float e = emb_s[n * C_CH + j];
                q[n] += e * wq; ak[n] += e * wk; av[n] += e * wv;
            }
        }
        float4* kd = (float4*)&k_s[t * 8];
        float4* vd = (float4*)&v_s[t * 8];
        kd[0] = make_float4(ak[0], ak[1], ak[2], ak[3]);
        kd[1] = make_float4(ak[4], ak[5], ak[6], ak[7]);
        vd[0] = make_float4(av[0], av[1], av[2], av[3]);
        vd[1] = make_float4(av[4], av[5], av[6], av[7]);
    }
    __syncthreads();
    const int h = t & 7;
    float arow[C_CH];
    float sum = 0.f, ssq = 0.f;
    #pragma unroll
    for (int d = 0; d < C_CH; ++d) {
        const float4* kr = (const float4*)&k_s[(d * HEADS + h) * 8];
        const float4 k0 = kr[0], k1 = kr[1];
        float s = q[0]*k0.x + q[1]*k0.y + q[2]*k0.z + q[3]*k0.w
                + q[4]*k1.x + q[5]*k1.y + q[6]*k1.z + q[7]*k1.w;
        arow[d] = s; sum += s; ssq += s * s;
    }
    #pragma unroll
    for (int m = 8; m < 64; m <<= 1) { sum += __shfl_xor(sum, m); ssq += __shfl_xor(ssq, m); }
    const int wv_id = t >> 6;
    if ((t & 63) < 8) { part_sum[wv_id * 8 + h] = sum; part_ssq[wv_id * 8 + h] = ssq; }
    __syncthreads();
    sum = 0.f; ssq = 0.f;
    #pragma unroll
    for (int w2 = 0; w2 < 8; ++w2) { sum += part_sum[w2 * 8 + h]; ssq += part_ssq[w2 * 8 + h]; }
    const float mean = sum * (1.f / 4096.f);
    const float var  = ssq * (1.f / 4096.f) - mean * mean;
    const float rstd = rsqrtf(var + 1e-5f);
    float mx = -3.0e38f;
    #pragma unroll
    for (int d = 0; d < C_CH; ++d) { arow[d] = (arow[d] - mean) * rstd; mx = fmaxf(mx, arow[d]); }
    float es = 0.f;
    #pragma unroll
    for (int d = 0; d < C_CH; ++d) { arow[d] = __expf(arow[d] - mx); es += arow[d]; }
    const float inv = 1.f / es;
    float c[N_TOK];
    #pragma unroll
    for (int n = 0; n < N_TOK; ++n) c[n] = 0.f;
    #pragma unroll
    for (int d = 0; d < C_CH; ++d) {
        const float4* vr = (const float4*)&v_s[(d * HEADS + h) * 8];
        const float4 v0 = vr[0], v1 = vr[1];
        const float a = arow[d] * inv;
        c[0]+=a*v0.x; c[1]+=a*v0.y; c[2]+=a*v0.z; c[3]+=a*v0.w;
        c[4]+=a*v1.x; c[5]+=a*v1.y; c[6]+=a*v1.z; c[7]+=a*v1.w;
    }
    __syncthreads();
    #pragma unroll
    for (int n = 0; n < N_TOK; ++n) ctx_s[n * 512 + t] = c[n];
    __syncthreads();
    const int n_o = t >> 6, gg = t & 15, ss = (t >> 4) & 3;
    const float4* Wo4 = (const float4*)Wo;
    const float4* cx4 = (const float4*)&ctx_s[n_o * 512 + ss * 128];
    float4 acc = make_float4(0.f, 0.f, 0.f, 0.f);
    #pragma unroll 8
    for (int kk = 0; kk < 128; kk += 4) {
        const float4 cc = cx4[kk >> 2];
        const int kbm = (ss * 128 + kk) * 16 + gg;
        const float4 w0 = Wo4[kbm], w1 = Wo4[kbm + 16], w2 = Wo4[kbm + 32], w3_ = Wo4[kbm + 48];
        acc.x += cc.x*w0.x + cc.y*w1.x + cc.z*w2.x + cc.w*w3_.x;
        acc.y += cc.x*w0.y + cc.y*w1.y + cc.z*w2.y + cc.w*w3_.y;
        acc.z += cc.x*w0.z + cc.y*w1.z + cc.z*w2.z + cc.w*w3_.z;
        acc.w += cc.x*w0.w + cc.y*w1.w + cc.z*w2.w + cc.w*w3_.w;
    }
    acc.x += __shfl_xor(acc.x, 16); acc.x += __shfl_xor(acc.x, 32);
    acc.y += __shfl_xor(acc.y, 16); acc.y += __shfl_xor(acc.y, 32);
    acc.z += __shfl_xor(acc.z, 16); acc.z += __shfl_xor(acc.z, 32);
    acc.w += __shfl_xor(acc.w, 16); acc.w += __shfl_xor(acc.w, 32);
    if (ss == 0) {
        const int b = bp / 27, r = bp % 27;
        const int dd = r / 9, hh = (r / 3) % 3, ww = r % 3;
        const int token = ((((dd*2 + ((n_o>>2)&1))*3 + hh)*2 + ((n_o>>1)&1))*3 + ww)*2 + (n_o&1);
        *(float4*)&out[(b * 216 + token) * C_CH + gg * 4] = acc;
    }
}

extern "C" void kernel_launch(void* const* d_in, const int* in_sizes, int n_in,
                              void* d_out, int out_size, void* d_ws, size_t ws_size,
                              hipStream_t stream) {
    const float* emb = (const float*)d_in[0];
    const float* Wq  = (const float*)d_in[1];
    const float* Wk  = (const float*)d_in[2];
    const float* Wv  = (const float*)d_in[3];
    const float* Wo  = (const float*)d_in[4];
    float* out = (float*)d_out;
    const int Bp = in_sizes[0] / (N_TOK * C_CH);   // 3456

    if (ws_size >= 262144 * sizeof(u16)) {
        u16* ws = (u16*)d_ws;
        prep_weights<<<512, 512, 0, stream>>>(Wq, Wk, Wv, Wo, ws);
        fused_attn_mfma<<<Bp / 2, 512, 0, stream>>>(emb, ws, ws + 196608, out);
    } else {
        fused_fallback<<<Bp, 512, 0, stream>>>(emb, Wq, Wk, Wv, Wo, out);
    }
}

// Round 4
// 121.859 us; speedup vs baseline: 3.5343x; 1.1511x over previous
//
#include <hip/hip_runtime.h>
#include <stdint.h>

typedef unsigned short u16;
typedef unsigned int   u32;
typedef short short8 __attribute__((ext_vector_type(8)));
typedef float f32x4  __attribute__((ext_vector_type(4)));

#define MFMA(a, b, c) __builtin_amdgcn_mfma_f32_16x16x32_bf16((a), (b), (c), 0, 0, 0)

static __device__ __forceinline__ u16 bf_trunc(float x) {
    return (u16)(__builtin_bit_cast(u32, x) >> 16);
}
static __device__ __forceinline__ float bf_to_f(u16 h) {
    u32 b = ((u32)h) << 16; return __builtin_bit_cast(float, b);
}
static __device__ __forceinline__ u16 bf_rne(float x) {
    u32 b = __builtin_bit_cast(u32, x);
    return (u16)((b + 0x7FFF + ((b >> 16) & 1)) >> 16);
}

// ---------------------------------------------------------------------------
// prep kernel (unchanged from R3): weights -> MFMA-B-fragment bf16 hi/lo.
// frags 0..191 = {Wq,Wk,Wv} (frag = mat*64 + kt*32 + nt), 192..255 = Wo
// (frag = 192 + kt*4 + nt). elem (frag,sel,lane,j) at frag*1024+sel*512+l*8+j.
// B[k][col], k = kt*32 + (l>>4)*8 + j, col = nt*16 + (l&15).
// ---------------------------------------------------------------------------
__global__ __launch_bounds__(512) void prep_weights(
    const float* __restrict__ Wq, const float* __restrict__ Wk,
    const float* __restrict__ Wv, const float* __restrict__ Wo,
    u16* __restrict__ ws)
{
    int idx = blockIdx.x * 512 + threadIdx.x;     // 0..262143
    int frag = idx >> 10;
    int rem  = idx & 1023;
    int sel  = rem >> 9;
    int l    = (rem >> 3) & 63;
    int j    = rem & 7;
    float v;
    if (frag < 192) {
        int mat = frag >> 6;
        int kt  = (frag >> 5) & 1;
        int nt  = frag & 31;
        int k   = kt * 32 + (l >> 4) * 8 + j;
        int col = nt * 16 + (l & 15);
        const float* W = (mat == 0) ? Wq : ((mat == 1) ? Wk : Wv);
        v = W[k * 512 + col];
    } else {
        int f   = frag - 192;
        int kt  = f >> 2;
        int nt  = f & 3;
        int k   = kt * 32 + (l >> 4) * 8 + j;
        int col = nt * 16 + (l & 15);
        v = Wo[k * 64 + col];
    }
    u16 hi = bf_trunc(v);
    u16 o  = hi;
    if (sel) o = bf_trunc(v - bf_to_f(hi));
    ws[idx] = o;
}

// ---------------------------------------------------------------------------
// main kernel: 1 patch per block, 512 threads (8 waves), wave w = head w.
// LDS arena (u16):
//   q_pk [0..8191]      : [ph=8][sel=2][c^ph = 64][8 tok]
//   k_pk [8192..16383]  : same
//   v_b  [16384..20479] : [ph=8][n=8][ d ^ ((ph ^ 2(n&3))<<3) = 64 ]
// overlays (after the relevant barrier):
//   chunkA(w) = arena + w*1024, chunkB(w) = arena + 8192 + w*1024 (P half-map)
//   ctxA_hi [0..4159] = [m=8][520], ctxA_lo [4160..8319]
//   partials f32 @ u16 16384 (4 KB)
// ---------------------------------------------------------------------------
__global__ __launch_bounds__(512, 4) void fused_attn_mfma(
    const float* __restrict__ emb,
    const u16*  __restrict__ w3,     // 192 qkv frags
    const u16*  __restrict__ wo,     // 64 Wo frags
    float* __restrict__ out)
{
    __shared__ u16 arena[20480];
    u16* q_pk = arena;
    u16* k_pk = arena + 8192;
    u16* v_b  = arena + 16384;

    const int t   = threadIdx.x;
    const int l   = t & 63;
    const int w   = t >> 6;        // wave = head
    const int g   = l >> 4;
    const int l15 = l & 15;
    const int bp  = blockIdx.x;

    // ---- P1: QKV projection. A-frag (emb) straight from global; rows 8-15
    //      of the M=16 tile are duplicates (their C rows are never read). ----
    short8 aeh[2], ael[2];
    {
        const float* eb = emb + (size_t)bp * 512 + (l15 & 7) * 64 + g * 8;
        #pragma unroll
        for (int kt = 0; kt < 2; ++kt) {
            float4 e0 = *(const float4*)(eb + kt * 32);
            float4 e1 = *(const float4*)(eb + kt * 32 + 4);
            float ev[8] = {e0.x, e0.y, e0.z, e0.w, e1.x, e1.y, e1.z, e1.w};
            #pragma unroll
            for (int j = 0; j < 8; ++j) {
                u16 hi = bf_trunc(ev[j]);
                aeh[kt][j] = (short)hi;
                ael[kt][j] = (short)bf_trunc(ev[j] - bf_to_f(hi));
            }
        }
    }
    #pragma unroll
    for (int i = 0; i < 12; ++i) {
        int tid = w * 12 + i;          // 0..95
        int mat = tid >> 5;            // 0=q 1=k 2=v
        int nt  = tid & 31;
        f32x4 acc = {0.f, 0.f, 0.f, 0.f};
        #pragma unroll
        for (int kt = 0; kt < 2; ++kt) {
            const u16* bb = &w3[(mat * 64 + kt * 32 + nt) * 1024];
            short8 bh = *(const short8*)&bb[l * 8];
            short8 bl = *(const short8*)&bb[512 + l * 8];
            acc = MFMA(aeh[kt], bh, acc);
            acc = MFMA(ael[kt], bh, acc);
            acc = MFMA(aeh[kt], bl, acc);
        }
        int col = nt * 16 + l15;       // output column in 512
        int cc  = col >> 3;            // channel
        int hh  = col & 7;             // head (= ph)
        if (mat < 2) {
            // bf16 hi/lo; exchange halves with lane^16 so g=0 writes the full
            // hi token-row and g=1 the full lo row as one b128.
            u16 h0 = bf_trunc(acc[0]), h1 = bf_trunc(acc[1]);
            u16 h2 = bf_trunc(acc[2]), h3 = bf_trunc(acc[3]);
            u16 q0 = bf_trunc(acc[0] - bf_to_f(h0)), q1 = bf_trunc(acc[1] - bf_to_f(h1));
            u16 q2 = bf_trunc(acc[2] - bf_to_f(h2)), q3 = bf_trunc(acc[3] - bf_to_f(h3));
            u32 hiA = (u32)h0 | ((u32)h1 << 16), hiB = (u32)h2 | ((u32)h3 << 16);
            u32 loA = (u32)q0 | ((u32)q1 << 16), loB = (u32)q2 | ((u32)q3 << 16);
            u32 s0 = (g & 1) ? hiA : loA;
            u32 s1 = (g & 1) ? hiB : loB;
            u32 r0 = (u32)__shfl_xor((int)s0, 16);
            u32 r1 = (u32)__shfl_xor((int)s1, 16);
            if (g < 2) {
                uint4 row;
                if (g == 0) { row.x = hiA; row.y = hiB; row.z = r0;  row.w = r1;  }
                else        { row.x = r0;  row.y = r1;  row.z = loA; row.w = loB; }
                u16* base = (mat == 0) ? q_pk : k_pk;
                *(uint4*)&base[((hh * 2 + g) * 64 + (cc ^ hh)) * 8] = row;
            }
        } else {
            // v: bf16 rne; pair adjacent channels via lane^8 into u32 words
            u16 a0 = bf_rne(acc[0]), a1 = bf_rne(acc[1]);
            u16 a2 = bf_rne(acc[2]), a3 = bf_rne(acc[3]);
            u32 send = (l15 & 8) ? ((u32)a0 | ((u32)a1 << 16))
                                 : ((u32)a2 | ((u32)a3 << 16));
            u32 recv = (u32)__shfl_xor((int)send, 8);
            if (g < 2) {
                int d0 = cc & ~1;
                u32 wA, wB; int rA, rB;
                if (!(l15 & 8)) {
                    wA = (u32)a0 | ((recv & 0xffffu) << 16);
                    wB = (u32)a1 | ((recv >> 16) << 16);
                    rA = 0; rB = 1;
                } else {
                    wA = (recv & 0xffffu) | ((u32)a2 << 16);
                    wB = (recv >> 16)     | ((u32)a3 << 16);
                    rA = 2; rB = 3;
                }
                int nA = g * 4 + rA, nB = g * 4 + rB;
                int sA = hh ^ ((nA & 3) << 1), sB = hh ^ ((nB & 3) << 1);
                *(u32*)&v_b[(hh * 8 + nA) * 64 + (d0 ^ (sA << 3))] = wA;
                *(u32*)&v_b[(hh * 8 + nB) * 64 + (d0 ^ (sB << 3))] = wB;
            }
        }
    }
    __syncthreads();

    // ---- P2: channel attention for head h = w ----
    const int h = w;
    const short8 z8 = {0, 0, 0, 0, 0, 0, 0, 0};

    // k-slot packing: slot0 = q_hi*k_hi, slot1 = q_lo*k_hi, slot2 = q_hi*k_lo,
    // slot3 = 0 (A-side zero).  One MFMA per tile with full bf16x3 precision.
    short8 qa[4], kb[4];
    {
        int selq = (g == 1) ? 1 : 0;
        int selk = (g == 2) ? 1 : 0;
        #pragma unroll
        for (int mt = 0; mt < 4; ++mt) {
            int c = mt * 16 + l15;
            short8 xq = *(const short8*)&q_pk[((h * 2 + selq) * 64 + (c ^ h)) * 8];
            qa[mt] = (g == 3) ? z8 : xq;
            kb[mt] = *(const short8*)&k_pk[((h * 2 + selk) * 64 + (c ^ h)) * 8];
        }
    }
    f32x4 att[4][4];
    #pragma unroll
    for (int mt = 0; mt < 4; ++mt)
        #pragma unroll
        for (int nt = 0; nt < 4; ++nt) {
            f32x4 z = {0.f, 0.f, 0.f, 0.f};
            att[mt][nt] = MFMA(qa[mt], kb[nt], z);
        }

    // instance-norm stats over the whole 64x64 map (one wave owns it)
    float sum = 0.f, ssq = 0.f;
    #pragma unroll
    for (int mt = 0; mt < 4; ++mt)
        #pragma unroll
        for (int nt = 0; nt < 4; ++nt)
            #pragma unroll
            for (int r = 0; r < 4; ++r) {
                float x = att[mt][nt][r];
                sum += x; ssq += x * x;
            }
    #pragma unroll
    for (int m = 1; m < 64; m <<= 1) {
        sum += __shfl_xor(sum, m);
        ssq += __shfl_xor(ssq, m);
    }
    float mu  = sum * (1.f / 4096.f);
    float var = ssq * (1.f / 4096.f) - mu * mu;
    float rs2 = rsqrtf(var + 1e-5f) * 1.44269504f;   // rstd*log2e
    float mu2 = mu * rs2;

    // exp (no max subtraction needed: |(a-mu)*rstd| <= 64 -> exp2 arg <= 92.3)
    #pragma unroll
    for (int mt = 0; mt < 4; ++mt)
        #pragma unroll
        for (int nt = 0; nt < 4; ++nt)
            #pragma unroll
            for (int r = 0; r < 4; ++r)
                att[mt][nt][r] = __builtin_amdgcn_exp2f(att[mt][nt][r] * rs2 - mu2);

    // V B-frag: cols 0..7 = v, col 8+ = ones (row-sum column, from registers)
    const short8 ones = {(short)0x3F80, (short)0x3F80, (short)0x3F80, (short)0x3F80,
                         (short)0x3F80, (short)0x3F80, (short)0x3F80, (short)0x3F80};
    short8 vb[2];
    {
        int n_  = l15 & 7;
        int sig = h ^ ((n_ & 3) << 1);
        #pragma unroll
        for (int kt = 0; kt < 2; ++kt) {
            short8 x = *(const short8*)&v_b[(h * 8 + n_) * 64 +
                                            ((kt * 32 + g * 8) ^ (sig << 3))];
            vb[kt] = (l15 >= 8) ? ones : x;
        }
    }

    // PV in two 32-row halves through the wave-private chunk (overlays own
    // q/k rows, which this wave has finished reading).
    u16* chA = arena + h * 1024;          // rows 0-15 of half
    u16* chB = arena + 8192 + h * 1024;   // rows 16-31 of half
    f32x4 ctx[4];
    #pragma unroll
    for (int half = 0; half < 2; ++half) {
        #pragma unroll
        for (int mt2 = 0; mt2 < 2; ++mt2) {
            int mt = half * 2 + mt2;
            u16* base = mt2 ? chB : chA;
            #pragma unroll
            for (int nt = 0; nt < 4; ++nt)
                #pragma unroll
                for (int r = 0; r < 4; ++r) {
                    int d = nt * 16 + l15;
                    base[(g * 4 + r) * 64 + (d ^ (g << 4))] = bf_rne(att[mt][nt][r]);
                }
        }
        #pragma unroll
        for (int mt2 = 0; mt2 < 2; ++mt2) {
            int MT = half * 2 + mt2;
            u16* base = mt2 ? chB : chA;
            f32x4 a0 = {0.f, 0.f, 0.f, 0.f};
            #pragma unroll
            for (int kt = 0; kt < 2; ++kt) {
                short8 aa = *(const short8*)&base[l15 * 64 +
                                ((kt * 32 + g * 8) ^ (((l15 >> 2) & 3) << 4))];
                a0 = MFMA(aa, vb[kt], a0);
            }
            ctx[MT] = a0;
        }
    }

    // normalize: row sums sit in column 8 (same g, lane l15==8)
    {
        int srcl = (l & 48) | 8;
        #pragma unroll
        for (int MT = 0; MT < 4; ++MT)
            #pragma unroll
            for (int r = 0; r < 4; ++r) {
                float rsum = __shfl(ctx[MT][r], srcl);
                ctx[MT][r] *= __builtin_amdgcn_rcpf(rsum);
            }
    }
    __syncthreads();   // all PV/LDS reads done before ctxA overlay

    // ---- ctx -> ctxA (bf16 hi/lo A-frags for P3) ----
    u16* ctxA_hi = arena;           // [m=8][520]
    u16* ctxA_lo = arena + 4160;
    if (l15 < 8) {
        #pragma unroll
        for (int MT = 0; MT < 4; ++MT)
            #pragma unroll
            for (int r = 0; r < 4; ++r) {
                int c = MT * 16 + g * 4 + r;
                int k = (c * 8 + h) ^ ((l15 & 3) << 4);
                float v = ctx[MT][r];
                u16 hi = bf_trunc(v);
                ctxA_hi[l15 * 520 + k] = hi;
                ctxA_lo[l15 * 520 + k] = bf_trunc(v - bf_to_f(hi));
            }
    }
    __syncthreads();

    // ---- P3: out = ctx @ Wo (bf16x3, split-K over wave pairs) ----
    {
        int nt  = w & 3;
        int kb0 = (w >> 2) * 8;
        int m   = l15 & 7;           // A rows 8-15 dup (C rows unread)
        f32x4 oacc = {0.f, 0.f, 0.f, 0.f};
        #pragma unroll
        for (int ki = 0; ki < 8; ++ki) {
            int kt = kb0 + ki;
            int kk = (kt * 32 + g * 8) ^ ((m & 3) << 4);
            short8 ah = *(const short8*)&ctxA_hi[m * 520 + kk];
            short8 al = *(const short8*)&ctxA_lo[m * 520 + kk];
            const u16* bb = &wo[(kt * 4 + nt) * 1024];
            short8 bh = *(const short8*)&bb[l * 8];
            short8 bl = *(const short8*)&bb[512 + l * 8];
            oacc = MFMA(ah, bh, oacc);
            oacc = MFMA(al, bh, oacc);
            oacc = MFMA(ah, bl, oacc);
        }
        float* part = (float*)&arena[16384];   // 4 KB over dead v_b
        if (w >= 4) *(f32x4*)&part[((w - 4) * 64 + l) * 4] = oacc;
        __syncthreads();
        if (w < 4 && g < 2) {
            f32x4 o2 = *(const f32x4*)&part[(w * 64 + l) * 4];
            oacc += o2;
            int col = nt * 16 + l15;
            int b = bp / 27, rr = bp % 27;
            int dd = rr / 9, hh2 = (rr / 3) % 3, ww2 = rr % 3;
            #pragma unroll
            for (int r = 0; r < 4; ++r) {
                int n = g * 4 + r;
                int token = ((((dd * 2 + (n >> 2)) * 3 + hh2) * 2 + ((n >> 1) & 1)) * 3
                             + ww2) * 2 + (n & 1);
                out[((size_t)b * 216 + token) * 64 + col] = oacc[r];
            }
        }
    }
}

// ---------------------------------------------------------------------------
// fallback (round-2 kernel) if ws is too small for weight preconversion
// ---------------------------------------------------------------------------
__global__ __launch_bounds__(512) void fused_fallback(
    const float* __restrict__ emb, const float* __restrict__ Wq,
    const float* __restrict__ Wk,  const float* __restrict__ Wv,
    const float* __restrict__ Wo,  float* __restrict__ out)
{
    __shared__ float emb_s[512];
    __shared__ float part_sum[64];
    __shared__ float part_ssq[64];
    __shared__ float kv_s[2 * 512 * 8];
    float* k_s = kv_s;
    float* v_s = kv_s + 512 * 8;
    float* ctx_s = kv_s;
    const int bp = blockIdx.x;
    const int t  = threadIdx.x;
    emb_s[t] = emb[bp * 512 + t];
    __syncthreads();
    float q[8];
    {
        float ak[8], av[8];
        #pragma unroll
        for (int n = 0; n < 8; ++n) { q[n] = 0.f; ak[n] = 0.f; av[n] = 0.f; }
        #pragma unroll 8
        for (int j = 0; j < 64; ++j) {
            const float wq = Wq[j * 512 + t], wk = Wk[j * 512 + t], wv = Wv[j * 512 + t];
            #pragma unroll
            for (int n = 0; n < 8; ++n) {
                const float e = emb_s[n * 64 + j];
                q[n] += e * wq; ak[n] += e * wk; av[n] += e * wv;
            }
        }
        float4* kd = (float4*)&k_s[t * 8];
        float4* vd = (float4*)&v_s[t * 8];
        kd[0] = make_float4(ak[0], ak[1], ak[2], ak[3]);
        kd[1] = make_float4(ak[4], ak[5], ak[6], ak[7]);
        vd[0] = make_float4(av[0], av[1], av[2], av[3]);
        vd[1] = make_float4(av[4], av[5], av[6], av[7]);
    }
    __syncthreads();
    const int h = t & 7;
    float arow[64];
    float sum = 0.f, ssq = 0.f;
    #pragma unroll
    for (int d = 0; d < 64; ++d) {
        const float4* kr = (const float4*)&k_s[(d * 8 + h) * 8];
        const float4 k0 = kr[0], k1 = kr[1];
        float s = q[0]*k0.x + q[1]*k0.y + q[2]*k0.z + q[3]*k0.w
                + q[4]*k1.x + q[5]*k1.y + q[6]*k1.z + q[7]*k1.w;
        arow[d] = s; sum += s; ssq += s * s;
    }
    #pragma unroll
    for (int m = 8; m < 64; m <<= 1) { sum += __shfl_xor(sum, m); ssq += __shfl_xor(ssq, m); }
    const int wv_id = t >> 6;
    if ((t & 63) < 8) { part_sum[wv_id * 8 + h] = sum; part_ssq[wv_id * 8 + h] = ssq; }
    __syncthreads();
    sum = 0.f; ssq = 0.f;
    #pragma unroll
    for (int w2 = 0; w2 < 8; ++w2) { sum += part_sum[w2 * 8 + h]; ssq += part_ssq[w2 * 8 + h]; }
    const float mean = sum * (1.f / 4096.f);
    const float var  = ssq * (1.f / 4096.f) - mean * mean;
    const float rstd = rsqrtf(var + 1e-5f);
    float mx = -3.0e38f;
    #pragma unroll
    for (int d = 0; d < 64; ++d) { arow[d] = (arow[d] - mean) * rstd; mx = fmaxf(mx, arow[d]); }
    float es = 0.f;
    #pragma unroll
    for (int d = 0; d < 64; ++d) { arow[d] = __expf(arow[d] - mx); es += arow[d]; }
    const float inv = 1.f / es;
    float c[8];
    #pragma unroll
    for (int n = 0; n < 8; ++n) c[n] = 0.f;
    #pragma unroll
    for (int d = 0; d < 64; ++d) {
        const float4* vr = (const float4*)&v_s[(d * 8 + h) * 8];
        const float4 v0 = vr[0], v1 = vr[1];
        const float a = arow[d] * inv;
        c[0]+=a*v0.x; c[1]+=a*v0.y; c[2]+=a*v0.z; c[3]+=a*v0.w;
        c[4]+=a*v1.x; c[5]+=a*v1.y; c[6]+=a*v1.z; c[7]+=a*v1.w;
    }
    __syncthreads();
    #pragma unroll
    for (int n = 0; n < 8; ++n) ctx_s[n * 512 + t] = c[n];
    __syncthreads();
    const int n_o = t >> 6, gg = t & 15, ss = (t >> 4) & 3;
    const float4* Wo4 = (const float4*)Wo;
    const float4* cx4 = (const float4*)&ctx_s[n_o * 512 + ss * 128];
    float4 acc = make_float4(0.f, 0.f, 0.f, 0.f);
    #pragma unroll 8
    for (int kk = 0; kk < 128; kk += 4) {
        const float4 cc = cx4[kk >> 2];
        const int kbm = (ss * 128 + kk) * 16 + gg;
        const float4 w0 = Wo4[kbm], w1 = Wo4[kbm + 16], w2 = Wo4[kbm + 32], w3_ = Wo4[kbm + 48];
        acc.x += cc.x*w0.x + cc.y*w1.x + cc.z*w2.x + cc.w*w3_.x;
        acc.y += cc.x*w0.y + cc.y*w1.y + cc.z*w2.y + cc.w*w3_.y;
        acc.z += cc.x*w0.z + cc.y*w1.z + cc.z*w2.z + cc.w*w3_.z;
        acc.w += cc.x*w0.w + cc.y*w1.w + cc.z*w2.w + cc.w*w3_.w;
    }
    acc.x += __shfl_xor(acc.x, 16); acc.x += __shfl_xor(acc.x, 32);
    acc.y += __shfl_xor(acc.y, 16); acc.y += __shfl_xor(acc.y, 32);
    acc.z += __shfl_xor(acc.z, 16); acc.z += __shfl_xor(acc.z, 32);
    acc.w += __shfl_xor(acc.w, 16); acc.w += __shfl_xor(acc.w, 32);
    if (ss == 0) {
        const int b = bp / 27, r = bp % 27;
        const int dd = r / 9, hh = (r / 3) % 3, ww = r % 3;
        const int token = ((((dd*2 + ((n_o>>2)&1))*3 + hh)*2 + ((n_o>>1)&1))*3 + ww)*2 + (n_o&1);
        *(float4*)&out[(b * 216 + token) * 64 + gg * 4] = acc;
    }
}

extern "C" void kernel_launch(void* const* d_in, const int* in_sizes, int n_in,
                              void* d_out, int out_size, void* d_ws, size_t ws_size,
                              hipStream_t stream) {
    const float* emb = (const float*)d_in[0];
    const float* Wq  = (const float*)d_in[1];
    const float* Wk  = (const float*)d_in[2];
    const float* Wv  = (const float*)d_in[3];
    const float* Wo  = (const float*)d_in[4];
    float* out = (float*)d_out;
    const int Bp = in_sizes[0] / 512;   // 3456

    if (ws_size >= 262144 * sizeof(u16)) {
        u16* ws = (u16*)d_ws;
        prep_weights<<<512, 512, 0, stream>>>(Wq, Wk, Wv, Wo, ws);
        fused_attn_mfma<<<Bp, 512, 0, stream>>>(emb, ws, ws + 196608, out);
    } else {
        fused_fallback<<<Bp, 512, 0, stream>>>(emb, Wq, Wk, Wv, Wo, out);
    }
}

// Round 6
// 97.593 us; speedup vs baseline: 4.4131x; 1.2486x over previous
//
#include <hip/hip_runtime.h>
#include <stdint.h>

typedef unsigned short u16;
typedef unsigned int   u32;
typedef short short8 __attribute__((ext_vector_type(8)));
typedef float f32x4  __attribute__((ext_vector_type(4)));

#define MFMA(a, b, c) __builtin_amdgcn_mfma_f32_16x16x32_bf16((a), (b), (c), 0, 0, 0)

static __device__ __forceinline__ u16 bf_trunc(float x) {
    return (u16)(__builtin_bit_cast(u32, x) >> 16);
}
static __device__ __forceinline__ float bf_to_f(u16 h) {
    u32 b = ((u32)h) << 16; return __builtin_bit_cast(float, b);
}
static __device__ __forceinline__ u16 bf_rne(float x) {
    u32 b = __builtin_bit_cast(u32, x);
    return (u16)((b + 0x7FFF + ((b >> 16) & 1)) >> 16);
}

// ---------------------------------------------------------------------------
// prep kernel (unchanged): weights -> MFMA-B-fragment bf16 hi/lo in ws.
// frags 0..191 = {Wq,Wk,Wv} (frag = mat*64 + kt*32 + nt), 192..255 = Wo
// (frag = 192 + kt*4 + nt). elem (frag,sel,lane,j) at frag*1024+sel*512+l*8+j.
// B[k][col], k = kt*32 + (l>>4)*8 + j, col = nt*16 + (l&15).
// ---------------------------------------------------------------------------
__global__ __launch_bounds__(512) void prep_weights(
    const float* __restrict__ Wq, const float* __restrict__ Wk,
    const float* __restrict__ Wv, const float* __restrict__ Wo,
    u16* __restrict__ ws)
{
    int idx = blockIdx.x * 512 + threadIdx.x;     // 0..262143
    int frag = idx >> 10;
    int rem  = idx & 1023;
    int sel  = rem >> 9;
    int l    = (rem >> 3) & 63;
    int j    = rem & 7;
    float v;
    if (frag < 192) {
        int mat = frag >> 6;
        int kt  = (frag >> 5) & 1;
        int nt  = frag & 31;
        int k   = kt * 32 + (l >> 4) * 8 + j;
        int col = nt * 16 + (l & 15);
        const float* W = (mat == 0) ? Wq : ((mat == 1) ? Wk : Wv);
        v = W[k * 512 + col];
    } else {
        int f   = frag - 192;
        int kt  = f >> 2;
        int nt  = f & 3;
        int k   = kt * 32 + (l >> 4) * 8 + j;
        int col = nt * 16 + (l & 15);
        v = Wo[k * 64 + col];
    }
    u16 hi = bf_trunc(v);
    u16 o  = hi;
    if (sel) o = bf_trunc(v - bf_to_f(hi));
    ws[idx] = o;
}

// ---------------------------------------------------------------------------
// main kernel: 2 patches per block, 512 threads (8 waves).
// wave w owns maps ph = 2w, 2w+1  (ph = p*8 + h, p = patch in block).
// LDS arena (u16):
//   q_pk [0..16383]      : [16 ph][2 sel][64 c'][8 tok], c' = c^h^(sel<<1)^(p<<2)
//   k_pk [16384..32767]  : same
//   v_b  [32768..40959]  : [16 ph][8 n][64 d'], d' = d ^ ((h^2(n&3))<<3)
// overlays:
//   P chunks (per wave, own region): chA = q_pk + ph*1024, chB = k_pk + ph*1024
//   ctxA_hi [16][520] @ 0 (q region), ctxA_lo @ 16384 (k region)
//   partials f32 (4 KB) @ v region
// ---------------------------------------------------------------------------
__global__ __launch_bounds__(512, 4) void fused_attn_mfma(
    const float* __restrict__ emb,
    const u16*  __restrict__ w3,     // 192 qkv frags
    const u16*  __restrict__ wo,     // 64 Wo frags
    float* __restrict__ out)
{
    __shared__ u16 arena[40960];
    u16* q_pk = arena;
    u16* k_pk = arena + 16384;
    u16* v_b  = arena + 32768;

    const int t   = threadIdx.x;
    const int l   = t & 63;
    const int w   = t >> 6;
    const int g   = l >> 4;
    const int l15 = l & 15;
    const int bp2 = blockIdx.x;    // 0..1727 (2 patches each)

    // ---- P1 A-frags: row m = l15 = p*8 + n (16 real rows) ----
    short8 aeh[2], ael[2];
    {
        const float* eb = emb + ((size_t)bp2 * 2 + (l15 >> 3)) * 512 + (l15 & 7) * 64 + g * 8;
        #pragma unroll
        for (int kt = 0; kt < 2; ++kt) {
            float4 e0 = *(const float4*)(eb + kt * 32);
            float4 e1 = *(const float4*)(eb + kt * 32 + 4);
            float ev[8] = {e0.x, e0.y, e0.z, e0.w, e1.x, e1.y, e1.z, e1.w};
            #pragma unroll
            for (int j = 0; j < 8; ++j) {
                u16 hi = bf_trunc(ev[j]);
                aeh[kt][j] = (short)hi;
                ael[kt][j] = (short)bf_trunc(ev[j] - bf_to_f(hi));
            }
        }
    }

    // ---- P1: QKV = emb @ {Wq,Wk,Wv}, bf16x3, 12 tiles/wave, 2 patches ----
    #pragma unroll
    for (int i = 0; i < 12; ++i) {
        int tid = w * 12 + i;          // 0..95
        int mat = tid >> 5;            // 0=q 1=k 2=v
        int nt  = tid & 31;
        f32x4 acc = {0.f, 0.f, 0.f, 0.f};
        #pragma unroll
        for (int kt = 0; kt < 2; ++kt) {
            const u16* bb = &w3[(mat * 64 + kt * 32 + nt) * 1024];
            short8 bh = *(const short8*)&bb[l * 8];
            short8 bl = *(const short8*)&bb[512 + l * 8];
            acc = MFMA(aeh[kt], bh, acc);
            acc = MFMA(ael[kt], bh, acc);
            acc = MFMA(aeh[kt], bl, acc);
        }
        // C/D: col = nt*16+l15 (-> channel cc, head hh); rows m = g*4+r,
        // m = p*8 + n  ->  p = g>>1, n = (g&1)*4 + r.
        int hh = l15 & 7;
        int cc = nt * 2 + (l15 >> 3);
        int p  = g >> 1;
        int ph = p * 8 + hh;
        if (mat < 2) {
            u16 h0 = bf_trunc(acc[0]), h1 = bf_trunc(acc[1]);
            u16 h2 = bf_trunc(acc[2]), h3 = bf_trunc(acc[3]);
            u16 q0 = bf_trunc(acc[0] - bf_to_f(h0)), q1 = bf_trunc(acc[1] - bf_to_f(h1));
            u16 q2 = bf_trunc(acc[2] - bf_to_f(h2)), q3 = bf_trunc(acc[3] - bf_to_f(h3));
            u32 hiA = (u32)h0 | ((u32)h1 << 16), hiB = (u32)h2 | ((u32)h3 << 16);
            u32 loA = (u32)q0 | ((u32)q1 << 16), loB = (u32)q2 | ((u32)q3 << 16);
            // exchange with lane^16 (g0<->g1 = patch0, g2<->g3 = patch1):
            // even g writes the full 8-token hi row, odd g the lo row.
            u32 s0 = (g & 1) ? hiA : loA;
            u32 s1 = (g & 1) ? hiB : loB;
            u32 r0 = (u32)__shfl_xor((int)s0, 16);
            u32 r1 = (u32)__shfl_xor((int)s1, 16);
            int sel = g & 1;
            int cp  = cc ^ hh ^ (sel << 1) ^ (p << 2);
            uint4 row;
            if (sel == 0) { row.x = hiA; row.y = hiB; row.z = r0;  row.w = r1;  }
            else          { row.x = r0;  row.y = r1;  row.z = loA; row.w = loB; }
            u16* base = (mat == 0) ? q_pk : k_pk;
            *(uint4*)&base[((ph * 2 + sel) * 64 + cp) * 8] = row;
        } else {
            // v: bf16 rne; pair adjacent channels via lane^8 (R4-proven path)
            u16 a0 = bf_rne(acc[0]), a1 = bf_rne(acc[1]);
            u16 a2 = bf_rne(acc[2]), a3 = bf_rne(acc[3]);
            u32 send = (l15 & 8) ? ((u32)a0 | ((u32)a1 << 16))
                                 : ((u32)a2 | ((u32)a3 << 16));
            u32 recv = (u32)__shfl_xor((int)send, 8);
            int d0 = nt * 2;
            u32 wA, wB; int rA;
            if (!(l15 & 8)) {   // own col d0, partner col d0+1; rows 0,1
                wA = (u32)a0 | ((recv & 0xffffu) << 16);
                wB = (u32)a1 | (recv & 0xffff0000u);
                rA = 0;
            } else {            // own col d0+1, partner col d0; rows 2,3
                wA = (recv & 0xffffu) | ((u32)a2 << 16);
                wB = (recv >> 16)     | ((u32)a3 << 16);
                rA = 2;
            }
            int nA = (g & 1) * 4 + rA, nB = nA + 1;
            int sA = hh ^ ((nA & 3) << 1), sB = hh ^ ((nB & 3) << 1);
            *(u32*)&v_b[(ph * 8 + nA) * 64 + (d0 ^ (sA << 3))] = wA;
            *(u32*)&v_b[(ph * 8 + nB) * 64 + (d0 ^ (sB << 3))] = wB;
        }
    }
    __syncthreads();

    // ---- P2: two (patch,head) maps per wave, sequential ----
    const short8 z8 = {0, 0, 0, 0, 0, 0, 0, 0};
    const short8 ones = {(short)0x3F80, (short)0x3F80, (short)0x3F80, (short)0x3F80,
                         (short)0x3F80, (short)0x3F80, (short)0x3F80, (short)0x3F80};
    f32x4 ctx[2][4];

    #pragma unroll
    for (int pp = 0; pp < 2; ++pp) {
        const int ph = 2 * w + pp;
        const int h  = ph & 7;
        const int p  = ph >> 3;

        // k-slot packed QK^T: slots0-7 q_hi*k_hi, 8-15 q_lo*k_hi, 16-23 q_hi*k_lo, 24-31 zero
        short8 kb[4];
        {
            int selk = (g == 2) ? 1 : 0;
            #pragma unroll
            for (int mt = 0; mt < 4; ++mt) {
                int c  = mt * 16 + l15;
                int ck = (c ^ h) ^ (selk << 1) ^ (p << 2);
                kb[mt] = *(const short8*)&k_pk[((ph * 2 + selk) * 64 + ck) * 8];
            }
        }
        f32x4 att[4][4];
        int selq = (g == 1) ? 1 : 0;
        __builtin_amdgcn_s_setprio(1);
        #pragma unroll
        for (int mt = 0; mt < 4; ++mt) {
            int c  = mt * 16 + l15;
            int cq = (c ^ h) ^ (selq << 1) ^ (p << 2);
            short8 xq = *(const short8*)&q_pk[((ph * 2 + selq) * 64 + cq) * 8];
            short8 qa = (g == 3) ? z8 : xq;
            #pragma unroll
            for (int nt = 0; nt < 4; ++nt) {
                f32x4 z = {0.f, 0.f, 0.f, 0.f};
                att[mt][nt] = MFMA(qa, kb[nt], z);
            }
        }
        __builtin_amdgcn_s_setprio(0);

        // instance-norm stats over the whole 64x64 map (wave-owned)
        float sum = 0.f, ssq = 0.f;
        #pragma unroll
        for (int mt = 0; mt < 4; ++mt)
            #pragma unroll
            for (int nt = 0; nt < 4; ++nt)
                #pragma unroll
                for (int r = 0; r < 4; ++r) {
                    float x = att[mt][nt][r];
                    sum += x; ssq += x * x;
                }
        #pragma unroll
        for (int m = 1; m < 64; m <<= 1) {
            sum += __shfl_xor(sum, m);
            ssq += __shfl_xor(ssq, m);
        }
        float mu  = sum * (1.f / 4096.f);
        float var = ssq * (1.f / 4096.f) - mu * mu;
        float rs2 = rsqrtf(var + 1e-5f) * 1.44269504f;
        float mu2 = mu * rs2;

        // exp (softmax shift-invariance: mean cancels; |z|<=64 -> no overflow)
        #pragma unroll
        for (int mt = 0; mt < 4; ++mt)
            #pragma unroll
            for (int nt = 0; nt < 4; ++nt)
                #pragma unroll
                for (int r = 0; r < 4; ++r)
                    att[mt][nt][r] = __builtin_amdgcn_exp2f(att[mt][nt][r] * rs2 - mu2);

        // V B-frag: cols 0..7 = v tokens, cols 8+ = ones (row-sum column)
        short8 vb[2];
        {
            int n_  = l15 & 7;
            int sig = h ^ ((n_ & 3) << 1);
            #pragma unroll
            for (int kt = 0; kt < 2; ++kt) {
                short8 x = *(const short8*)&v_b[(ph * 8 + n_) * 64 +
                                                ((kt * 32 + g * 8) ^ (sig << 3))];
                vb[kt] = (l15 >= 8) ? ones : x;
            }
        }

        // PV in two 32-row halves through this wave's OWN q/k sub-regions
        u16* chA = q_pk + ph * 1024;   // rows 0-15 of half
        u16* chB = k_pk + ph * 1024;   // rows 16-31 of half
        #pragma unroll
        for (int half = 0; half < 2; ++half) {
            #pragma unroll
            for (int mt2 = 0; mt2 < 2; ++mt2) {
                int mt = half * 2 + mt2;
                u16* base = mt2 ? chB : chA;
                #pragma unroll
                for (int nt = 0; nt < 4; ++nt) {
                    int dx = (nt * 16 + l15) ^ (g << 4);
                    base[(g * 4 + 0) * 64 + dx] = bf_rne(att[mt][nt][0]);
                    base[(g * 4 + 1) * 64 + dx] = bf_rne(att[mt][nt][1]);
                    base[(g * 4 + 2) * 64 + dx] = bf_rne(att[mt][nt][2]);
                    base[(g * 4 + 3) * 64 + dx] = bf_rne(att[mt][nt][3]);
                }
            }
            __builtin_amdgcn_s_setprio(1);
            #pragma unroll
            for (int mt2 = 0; mt2 < 2; ++mt2) {
                int MT = half * 2 + mt2;
                u16* base = mt2 ? chB : chA;
                f32x4 a0 = {0.f, 0.f, 0.f, 0.f};
                #pragma unroll
                for (int kt = 0; kt < 2; ++kt) {
                    short8 aa = *(const short8*)&base[l15 * 64 +
                                    ((kt * 32 + g * 8) ^ (((l15 >> 2) & 3) << 4))];
                    a0 = MFMA(aa, vb[kt], a0);
                }
                ctx[pp][MT] = a0;
            }
            __builtin_amdgcn_s_setprio(0);
        }

        // normalize: row sums sit in col 8 -> lane (g<<4)|8
        {
            int srcl = (l & 48) | 8;
            #pragma unroll
            for (int MT = 0; MT < 4; ++MT)
                #pragma unroll
                for (int r = 0; r < 4; ++r) {
                    float rsum = __shfl(ctx[pp][MT][r], srcl);
                    ctx[pp][MT][r] *= __builtin_amdgcn_rcpf(rsum);
                }
        }
    }
    __syncthreads();   // all waves done with q/k/v before ctxA overlay

    // ---- ctx -> ctxA (bf16 hi/lo A-frags, rows m = p*8+n, cols k = c*8+h) ----
    u16* ctxA_hi = arena;            // [16][520]
    u16* ctxA_lo = arena + 16384;
    if (l15 < 8) {
        #pragma unroll
        for (int pp = 0; pp < 2; ++pp) {
            int ph = 2 * w + pp;
            int h  = ph & 7;
            int p  = ph >> 3;
            int m  = p * 8 + l15;
            int swz = (m & 3) << 4;
            #pragma unroll
            for (int MT = 0; MT < 4; ++MT)
                #pragma unroll
                for (int r = 0; r < 4; ++r) {
                    int c = MT * 16 + g * 4 + r;
                    int k = (c * 8 + h) ^ swz;
                    float v = ctx[pp][MT][r];
                    u16 hi = bf_trunc(v);
                    ctxA_hi[m * 520 + k] = hi;
                    ctxA_lo[m * 520 + k] = bf_trunc(v - bf_to_f(hi));
                }
        }
    }
    __syncthreads();

    // ---- P3: out = ctx @ Wo (bf16x3, split-K over wave pairs), 16 real rows ----
    {
        int nt  = w & 3;
        int kb0 = (w >> 2) * 8;
        int m   = l15;
        f32x4 oacc = {0.f, 0.f, 0.f, 0.f};
        #pragma unroll
        for (int ki = 0; ki < 8; ++ki) {
            int kt = kb0 + ki;
            int kk = (kt * 32 + g * 8) ^ ((m & 3) << 4);
            short8 ah = *(const short8*)&ctxA_hi[m * 520 + kk];
            short8 al = *(const short8*)&ctxA_lo[m * 520 + kk];
            const u16* bb = &wo[(kt * 4 + nt) * 1024];
            short8 bh = *(const short8*)&bb[l * 8];
            short8 bl = *(const short8*)&bb[512 + l * 8];
            oacc = MFMA(ah, bh, oacc);
            oacc = MFMA(al, bh, oacc);
            oacc = MFMA(ah, bl, oacc);
        }
        float* part = (float*)&v_b[0];     // 4 KB over dead v region
        if (w >= 4) *(f32x4*)&part[((w - 4) * 64 + l) * 4] = oacc;
        __syncthreads();
        if (w < 4) {
            f32x4 o2 = *(const f32x4*)&part[(w * 64 + l) * 4];
            oacc += o2;
            int col = nt * 16 + l15;
            int p   = g >> 1;
            int bp  = bp2 * 2 + p;
            int b   = bp / 27, rr = bp % 27;
            int dd  = rr / 9, hh2 = (rr / 3) % 3, ww2 = rr % 3;
            #pragma unroll
            for (int r = 0; r < 4; ++r) {
                int n = (g & 1) * 4 + r;
                int token = ((((dd * 2 + (n >> 2)) * 3 + hh2) * 2 + ((n >> 1) & 1)) * 3
                             + ww2) * 2 + (n & 1);
                out[((size_t)b * 216 + token) * 64 + col] = oacc[r];
            }
        }
    }
}

// ---------------------------------------------------------------------------
// fallback (round-2 kernel) if ws is too small for weight preconversion
// ---------------------------------------------------------------------------
__global__ __launch_bounds__(512) void fused_fallback(
    const float* __restrict__ emb, const float* __restrict__ Wq,
    const float* __restrict__ Wk,  const float* __restrict__ Wv,
    const float* __restrict__ Wo,  float* __restrict__ out)
{
    __shared__ float emb_s[512];
    __shared__ float part_sum[64];
    __shared__ float part_ssq[64];
    __shared__ float kv_s[2 * 512 * 8];
    float* k_s = kv_s;
    float* v_s = kv_s + 512 * 8;
    float* ctx_s = kv_s;
    const int bp = blockIdx.x;
    const int t  = threadIdx.x;
    emb_s[t] = emb[bp * 512 + t];
    __syncthreads();
    float q[8];
    {
        float ak[8], av[8];
        #pragma unroll
        for (int n = 0; n < 8; ++n) { q[n] = 0.f; ak[n] = 0.f; av[n] = 0.f; }
        #pragma unroll 8
        for (int j = 0; j < 64; ++j) {
            const float wq = Wq[j * 512 + t], wk = Wk[j * 512 + t], wv = Wv[j * 512 + t];
            #pragma unroll
            for (int n = 0; n < 8; ++n) {
                const float e = emb_s[n * 64 + j];
                q[n] += e * wq; ak[n] += e * wk; av[n] += e * wv;
            }
        }
        float4* kd = (float4*)&k_s[t * 8];
        float4* vd = (float4*)&v_s[t * 8];
        kd[0] = make_float4(ak[0], ak[1], ak[2], ak[3]);
        kd[1] = make_float4(ak[4], ak[5], ak[6], ak[7]);
        vd[0] = make_float4(av[0], av[1], av[2], av[3]);
        vd[1] = make_float4(av[4], av[5], av[6], av[7]);
    }
    __syncthreads();
    const int h = t & 7;
    float arow[64];
    float sum = 0.f, ssq = 0.f;
    #pragma unroll
    for (int d = 0; d < 64; ++d) {
        const float4* kr = (const float4*)&k_s[(d * 8 + h) * 8];
        const float4 k0 = kr[0], k1 = kr[1];
        float s = q[0]*k0.x + q[1]*k0.y + q[2]*k0.z + q[3]*k0.w
                + q[4]*k1.x + q[5]*k1.y + q[6]*k1.z + q[7]*k1.w;
        arow[d] = s; sum += s; ssq += s * s;
    }
    #pragma unroll
    for (int m = 8; m < 64; m <<= 1) { sum += __shfl_xor(sum, m); ssq += __shfl_xor(ssq, m); }
    const int wv_id = t >> 6;
    if ((t & 63) < 8) { part_sum[wv_id * 8 + h] = sum; part_ssq[wv_id * 8 + h] = ssq; }
    __syncthreads();
    sum = 0.f; ssq = 0.f;
    #pragma unroll
    for (int w2 = 0; w2 < 8; ++w2) { sum += part_sum[w2 * 8 + h]; ssq += part_ssq[w2 * 8 + h]; }
    const float mean = sum * (1.f / 4096.f);
    const float var  = ssq * (1.f / 4096.f) - mean * mean;
    const float rstd = rsqrtf(var + 1e-5f);
    float mx = -3.0e38f;
    #pragma unroll
    for (int d = 0; d < 64; ++d) { arow[d] = (arow[d] - mean) * rstd; mx = fmaxf(mx, arow[d]); }
    float es = 0.f;
    #pragma unroll
    for (int d = 0; d < 64; ++d) { arow[d] = __expf(arow[d] - mx); es += arow[d]; }
    const float inv = 1.f / es;
    float c[8];
    #pragma unroll
    for (int n = 0; n < 8; ++n) c[n] = 0.f;
    #pragma unroll
    for (int d = 0; d < 64; ++d) {
        const float4* vr = (const float4*)&v_s[(d * 8 + h) * 8];
        const float4 v0 = vr[0], v1 = vr[1];
        const float a = arow[d] * inv;
        c[0]+=a*v0.x; c[1]+=a*v0.y; c[2]+=a*v0.z; c[3]+=a*v0.w;
        c[4]+=a*v1.x; c[5]+=a*v1.y; c[6]+=a*v1.z; c[7]+=a*v1.w;
    }
    __syncthreads();
    #pragma unroll
    for (int n = 0; n < 8; ++n) ctx_s[n * 512 + t] = c[n];
    __syncthreads();
    const int n_o = t >> 6, gg = t & 15, ss = (t >> 4) & 3;
    const float4* Wo4 = (const float4*)Wo;
    const float4* cx4 = (const float4*)&ctx_s[n_o * 512 + ss * 128];
    float4 acc = make_float4(0.f, 0.f, 0.f, 0.f);
    #pragma unroll 8
    for (int kk = 0; kk < 128; kk += 4) {
        const float4 cc = cx4[kk >> 2];
        const int kbm = (ss * 128 + kk) * 16 + gg;
        const float4 w0 = Wo4[kbm], w1 = Wo4[kbm + 16], w2 = Wo4[kbm + 32], w3_ = Wo4[kbm + 48];
        acc.x += cc.x*w0.x + cc.y*w1.x + cc.z*w2.x + cc.w*w3_.x;
        acc.y += cc.x*w0.y + cc.y*w1.y + cc.z*w2.y + cc.w*w3_.y;
        acc.z += cc.x*w0.z + cc.y*w1.z + cc.z*w2.z + cc.w*w3_.z;
        acc.w += cc.x*w0.w + cc.y*w1.w + cc.z*w2.w + cc.w*w3_.w;
    }
    acc.x += __shfl_xor(acc.x, 16); acc.x += __shfl_xor(acc.x, 32);
    acc.y += __shfl_xor(acc.y, 16); acc.y += __shfl_xor(acc.y, 32);
    acc.z += __shfl_xor(acc.z, 16); acc.z += __shfl_xor(acc.z, 32);
    acc.w += __shfl_xor(acc.w, 16); acc.w += __shfl_xor(acc.w, 32);
    if (ss == 0) {
        const int b = bp / 27, r = bp % 27;
        const int dd = r / 9, hh = (r / 3) % 3, ww = r % 3;
        const int token = ((((dd*2 + ((n_o>>2)&1))*3 + hh)*2 + ((n_o>>1)&1))*3 + ww)*2 + (n_o&1);
        *(float4*)&out[(b * 216 + token) * 64 + gg * 4] = acc;
    }
}

extern "C" void kernel_launch(void* const* d_in, const int* in_sizes, int n_in,
                              void* d_out, int out_size, void* d_ws, size_t ws_size,
                              hipStream_t stream) {
    const float* emb = (const float*)d_in[0];
    const float* Wq  = (const float*)d_in[1];
    const float* Wk  = (const float*)d_in[2];
    const float* Wv  = (const float*)d_in[3];
    const float* Wo  = (const float*)d_in[4];
    float* out = (float*)d_out;
    const int Bp = in_sizes[0] / 512;   // 3456

    if (ws_size >= 262144 * sizeof(u16) && (Bp & 1) == 0) {
        u16* ws = (u16*)d_ws;
        prep_weights<<<512, 512, 0, stream>>>(Wq, Wk, Wv, Wo, ws);
        fused_attn_mfma<<<Bp / 2, 512, 0, stream>>>(emb, ws, ws + 196608, out);
    } else {
        fused_fallback<<<Bp, 512, 0, stream>>>(emb, Wq, Wk, Wv, Wo, out);
    }
}